// Round 10
// baseline (146.061 us; speedup 1.0000x reference)
//
#include <hip/hip_runtime.h>
#include <cstdint>

typedef __attribute__((ext_vector_type(8))) short short8;
typedef __attribute__((ext_vector_type(16))) float f32x16;
typedef __attribute__((ext_vector_type(4))) unsigned int uint4v;

__device__ inline uint32_t f2bf_rne(float f) {
    union { float f; uint32_t u; } x; x.f = f;
    return (x.u + 0x7FFF + ((x.u >> 16) & 1)) >> 16;
}
__device__ inline uint32_t fbits(float f) {
    union { float f; uint32_t u; } x; x.f = f;
    return x.u;
}

// Convert kernel fp32 [9][64][64] -> bf16 ktb (same order), init bias outputs.
__global__ void k_prep(const float* __restrict__ kk, uint16_t* __restrict__ ktb,
                       const float* __restrict__ buI, const float* __restrict__ blI,
                       float* __restrict__ buO, float* __restrict__ blO) {
    int i = blockIdx.x * 256 + threadIdx.x;
    if (i < 36864) ktb[i] = (uint16_t)f2bf_rne(kk[i]);
    else if (i < 36864 + 256) buO[i - 36864] = buI[i - 36864];
    else if (i < 36864 + 512) blO[i - 36864 - 256] = blI[i - 36864 - 256];
}

// Block: (b, UL, h, w-chunk of 8) = 4 fully-independent waves (no LDS, no barriers).
// B-fragments loaded DIRECTLY from global in MFMA layout; pack via v_perm truncation
// (1 inst per 2 elements; bf16-truncate error far under threshold).
__global__ __launch_bounds__(256, 3) void k_main(
    const float* __restrict__ wu, const float* __restrict__ wl,
    const uint16_t* __restrict__ ktb, const float* __restrict__ bias,
    float* __restrict__ outU, float* __restrict__ outL,
    float* __restrict__ buO, float* __restrict__ blO)
{
    int t  = threadIdx.x;
    int l  = t & 63;
    int wv = t >> 6;
    int o  = l & 31;            // n_out index (frag col, stride-1 in memory)
    int ch = l >> 5;            // co-band selector

    // XCD-chunk swizzle: h innermost within an XCD's contiguous chunk
    int bid  = blockIdx.x;
    int virt = (bid & 7) * 256 + (bid >> 3);
    int h    = virt & 31;
    int wc   = (virt >> 5) & 3;
    int UL   = (virt >> 7) & 1;
    int b    = virt >> 8;
    int w0   = wc * 8 + 2 * wv;   // wave's first owned w

    const float* src = UL ? wl : wu;
    float* dst  = UL ? outL : outU;
    float* bdst = UL ? blO : buO;

    float bp = 0.f;               // bias partial (this lane's o, its co-band)

    f32x16 acc[2][2];             // [tw][ci-half]
    #pragma unroll
    for (int a = 0; a < 2; a++)
        #pragma unroll
        for (int c = 0; c < 2; c++) acc[a][c] = (f32x16)0.f;

    // site validity (wave-uniform): ww = w0-1+si
    bool sv0 = (w0 != 0);         // si=0 OOB only when w0==0
    bool sv3 = (w0 != 30);        // si=3 OOB only when w0+2==32

    for (int r = 0; r < 3; r++) {
        int hh = h + 1 - r;                 // adjoint: out row h reads conv row h+1-kh
        if ((unsigned)hh >= 32u) continue;  // wave-uniform

        // per-site lane base pointers (floats): + co*32 + o, co = kidx*16 + ch*8 + e
        const float* sb[4];
        #pragma unroll
        for (int si = 0; si < 4; si++) {
            int ww = w0 - 1 + si;
            int wwc = ((unsigned)ww < 32u) ? ww : 0;
            sb[si] = src + ((size_t)b * 65536 + (size_t)(hh * 32 + wwc) * 64) * 32
                         + ch * 256 + o;
        }

        #pragma unroll
        for (int kidx = 0; kidx < 4; kidx++) {
            // A-fragments (verified layout), 6 x 16B from bf16 kernel
            short8 A[3][2];
            #pragma unroll
            for (int kw = 0; kw < 3; kw++)
                #pragma unroll
                for (int c = 0; c < 2; c++)
                    A[kw][c] = *(const short8*)&ktb[(((r * 3 + kw) * 64) + c * 32 + (l & 31)) * 64
                                                    + kidx * 16 + ch * 8];

            // issue all 4 sites' B loads (8 dwords each, imm-offset folded)
            float g[4][8];
            #pragma unroll
            for (int si = 0; si < 4; si++) {
                bool valid = (si == 0) ? sv0 : (si == 3) ? sv3 : true;
                if (valid) {
                    #pragma unroll
                    for (int e = 0; e < 8; e++)
                        g[si][e] = sb[si][kidx * 512 + e * 32];
                } else {
                    #pragma unroll
                    for (int e = 0; e < 8; e++) g[si][e] = 0.f;
                }
            }

            // bias: center row, wave's own columns (si=1 -> w0, si=2 -> w0+1)
            if (r == 1) {
                float4 b0 = *(const float4*)(bias + kidx * 16 + ch * 8);
                float4 b1 = *(const float4*)(bias + kidx * 16 + ch * 8 + 4);
                float bb[8] = {b0.x, b0.y, b0.z, b0.w, b1.x, b1.y, b1.z, b1.w};
                #pragma unroll
                for (int e = 0; e < 8; e++)
                    bp = fmaf(g[1][e], bb[e], fmaf(g[2][e], bb[e], bp));
            }

            // pack (v_perm truncation: 1 inst / 2 elems) + MFMA
            #pragma unroll
            for (int si = 0; si < 4; si++) {
                uint4v pw;
                #pragma unroll
                for (int pr = 0; pr < 4; pr++)
                    pw[pr] = __builtin_amdgcn_perm(fbits(g[si][2 * pr + 1]),
                                                   fbits(g[si][2 * pr]), 0x07060302u);
                short8 Bf = __builtin_bit_cast(short8, pw);
                #pragma unroll
                for (int tw = 0; tw < 2; tw++) {
                    int kw = tw + 2 - si;              // compile-time under unroll
                    if (kw >= 0 && kw <= 2) {
                        #pragma unroll
                        for (int c = 0; c < 2; c++)
                            acc[tw][c] = __builtin_amdgcn_mfma_f32_32x32x16_bf16(
                                A[kw][c], Bf, acc[tw][c], 0, 0, 0);
                    }
                }
            }
        }
    }

    // ---- bias reduction: lanes l and l^32 share o ----
    bp += __shfl_xor(bp, 32);
    if (l < 32) atomicAdd(&bdst[b * 32 + o], bp);

    // ---- stores: col = o (coalesced), row = (reg&3)+8*(reg>>2)+4*(lane>>5) ----
    #pragma unroll
    for (int tw = 0; tw < 2; tw++) {
        int w = w0 + tw;
        #pragma unroll
        for (int c = 0; c < 2; c++) {
            float* base = dst + ((size_t)b * 65536 + (size_t)(h * 32 + w) * 64 + c * 32) * 32;
            #pragma unroll
            for (int reg = 0; reg < 16; reg++) {
                int row = (reg & 3) + 8 * (reg >> 2) + 4 * (l >> 5);
                base[row * 32 + o] = acc[tw][c][reg];
            }
        }
    }
}

extern "C" void kernel_launch(void* const* d_in, const int* in_sizes, int n_in,
                              void* d_out, int out_size, void* d_ws, size_t ws_size,
                              hipStream_t stream) {
    const float* wu   = (const float*)d_in[1];
    const float* buI  = (const float*)d_in[2];
    const float* wl   = (const float*)d_in[3];
    const float* blI  = (const float*)d_in[4];
    const float* kk   = (const float*)d_in[5];
    const float* bias = (const float*)d_in[6];

    float* out  = (float*)d_out;
    float* outU = out;
    float* buO  = out + 16777216;
    float* outL = out + 16777216 + 256;
    float* blO  = out + 2 * 16777216 + 256;

    uint16_t* ktb = (uint16_t*)d_ws;   // 73728 B

    k_prep<<<146, 256, 0, stream>>>(kk, ktb, buI, blI, buO, blO);
    k_main<<<2048, 256, 0, stream>>>(wu, wl, ktb, bias, outU, outL, buO, blO);
}

// Round 11
// 135.356 us; speedup vs baseline: 1.0791x; 1.0791x over previous
//
#include <hip/hip_runtime.h>
#include <cstdint>

typedef __attribute__((ext_vector_type(8))) short short8;
typedef __attribute__((ext_vector_type(16))) float f32x16;
typedef __attribute__((ext_vector_type(4))) unsigned int uint4v;

__device__ inline uint32_t f2bf_rne(float f) {
    union { float f; uint32_t u; } x; x.f = f;
    return (x.u + 0x7FFF + ((x.u >> 16) & 1)) >> 16;
}
__device__ inline uint32_t fbits(float f) {
    union { float f; uint32_t u; } x; x.f = f;
    return x.u;
}

// Convert kernel fp32 [9][64][64] -> bf16 ktb (same order), init bias outputs.
__global__ void k_prep(const float* __restrict__ kk, uint16_t* __restrict__ ktb,
                       const float* __restrict__ buI, const float* __restrict__ blI,
                       float* __restrict__ buO, float* __restrict__ blO) {
    int i = blockIdx.x * 256 + threadIdx.x;
    if (i < 36864) ktb[i] = (uint16_t)f2bf_rne(kk[i]);
    else if (i < 36864 + 256) buO[i - 36864] = buI[i - 36864];
    else if (i < 36864 + 512) blO[i - 36864 - 256] = blI[i - 36864 - 256];
}

// Block: (b, UL, h, w-chunk of 8) = 4 independent waves (no LDS, no barriers).
// 24 half-phases (r, kidx, site-pair), software-pipelined 1 ahead:
// ISSUE(p+1) -> COMPUTE(p). Parity-named register buffers, all indices static.
__global__ __launch_bounds__(256, 2) void k_main(
    const float* __restrict__ wu, const float* __restrict__ wl,
    const uint16_t* __restrict__ ktb, const float* __restrict__ bias,
    float* __restrict__ outU, float* __restrict__ outL,
    float* __restrict__ buO, float* __restrict__ blO)
{
    int t  = threadIdx.x;
    int l  = t & 63;
    int wv = t >> 6;
    int o  = l & 31;            // n_out index (frag col, stride-1 in memory)
    int ch = l >> 5;            // co-band selector

    // XCD-chunk swizzle
    int bid  = blockIdx.x;
    int virt = (bid & 7) * 256 + (bid >> 3);
    int h    = virt & 31;
    int wc   = (virt >> 5) & 3;
    int UL   = (virt >> 7) & 1;
    int b    = virt >> 8;
    int w0   = wc * 8 + 2 * wv;   // wave's first owned w

    const float* src = UL ? wl : wu;
    float* dst  = UL ? outL : outU;
    float* bdst = UL ? blO : buO;

    float bp = 0.f;

    f32x16 acc[2][2];
    #pragma unroll
    for (int a = 0; a < 2; a++)
        #pragma unroll
        for (int c = 0; c < 2; c++) acc[a][c] = (f32x16)0.f;

    // site validity (wave-uniform): ww = w0-1+si
    bool sval[4] = { w0 != 0, true, true, w0 != 30 };

    // rows: hh = h+1-r
    bool rv[3];
    const float* rowp[3];       // lane base: src + (b*65536 + hh*32*64)*32 + ch*256 + o
    #pragma unroll
    for (int r = 0; r < 3; r++) {
        int hh = h + 1 - r;
        rv[r] = (unsigned)hh < 32u;
        int hhc = rv[r] ? hh : 0;
        rowp[r] = src + ((size_t)b * 65536 + (size_t)hhc * 2048) * 32 + ch * 256 + o;
    }

    float gA[2][8], gB[2][8];   // [parity][e] for the 2 sites of a half-phase

    // ---- ISSUE(p) into parity buffer: 16 loads (2 sites x 8) ----
    auto ISSUE = [&](int p, float (&ga)[8], float (&gb)[8]) {
        int r = p >> 3, kidx = (p >> 1) & 3, sp = p & 1;
        int siA = 2 * sp, siB = 2 * sp + 1;
        if (rv[r]) {
            const float* rp = rowp[r] + (size_t)kidx * 512;
            if (sval[siA]) {
                const float* pa = rp + (size_t)(w0 - 1 + siA) * 2048;
                #pragma unroll
                for (int e = 0; e < 8; e++) ga[e] = pa[e * 32];
            } else {
                #pragma unroll
                for (int e = 0; e < 8; e++) ga[e] = 0.f;
            }
            if (sval[siB]) {
                const float* pb = rp + (size_t)(w0 - 1 + siB) * 2048;
                #pragma unroll
                for (int e = 0; e < 8; e++) gb[e] = pb[e * 32];
            } else {
                #pragma unroll
                for (int e = 0; e < 8; e++) gb[e] = 0.f;
            }
        }
    };

    // ---- COMPUTE(p) from parity buffer: bias + pack + 6 MFMA ----
    auto COMPUTE = [&](int p, float (&ga)[8], float (&gb)[8]) {
        int r = p >> 3, kidx = (p >> 1) & 3, sp = p & 1;
        if (!rv[r]) return;

        // A-fragments for this (r, kidx)
        short8 A[3][2];
        #pragma unroll
        for (int kw = 0; kw < 3; kw++)
            #pragma unroll
            for (int c = 0; c < 2; c++)
                A[kw][c] = *(const short8*)&ktb[(((r * 3 + kw) * 64) + c * 32 + (l & 31)) * 64
                                                + kidx * 16 + ch * 8];

        // bias: center row touches sites 1 (sp=0) and 2 (sp=1), each exactly once
        if (r == 1) {
            float4 b0 = *(const float4*)(bias + kidx * 16 + ch * 8);
            float4 b1 = *(const float4*)(bias + kidx * 16 + ch * 8 + 4);
            float bb[8] = {b0.x, b0.y, b0.z, b0.w, b1.x, b1.y, b1.z, b1.w};
            float (&gc)[8] = (sp == 0) ? gb : ga;   // site 1 or site 2
            #pragma unroll
            for (int e = 0; e < 8; e++) bp = fmaf(gc[e], bb[e], bp);
        }

        #pragma unroll
        for (int ss = 0; ss < 2; ss++) {
            int si = 2 * sp + ss;
            float (&g)[8] = ss ? gb : ga;
            uint4v pw;
            #pragma unroll
            for (int pr = 0; pr < 4; pr++)
                pw[pr] = __builtin_amdgcn_perm(fbits(g[2 * pr + 1]),
                                               fbits(g[2 * pr]), 0x07060302u);
            short8 Bf = __builtin_bit_cast(short8, pw);
            #pragma unroll
            for (int tw = 0; tw < 2; tw++) {
                int kw = tw + 2 - si;              // compile-time under unroll
                if (kw >= 0 && kw <= 2) {
                    #pragma unroll
                    for (int c = 0; c < 2; c++)
                        acc[tw][c] = __builtin_amdgcn_mfma_f32_32x32x16_bf16(
                            A[kw][c], Bf, acc[tw][c], 0, 0, 0);
                }
            }
        }
    };

    // ---- pipelined phase loop: ISSUE(p+1) before COMPUTE(p) ----
    ISSUE(0, gA[0], gB[0]);
    #pragma unroll
    for (int p = 0; p < 24; p++) {
        if (p < 23) ISSUE(p + 1, gA[(p + 1) & 1], gB[(p + 1) & 1]);
        COMPUTE(p, gA[p & 1], gB[p & 1]);
    }

    // ---- bias reduction: lanes l and l^32 share o ----
    bp += __shfl_xor(bp, 32);
    if (l < 32) atomicAdd(&bdst[b * 32 + o], bp);

    // ---- stores: col = o (coalesced), row = (reg&3)+8*(reg>>2)+4*(lane>>5) ----
    #pragma unroll
    for (int tw = 0; tw < 2; tw++) {
        int w = w0 + tw;
        #pragma unroll
        for (int c = 0; c < 2; c++) {
            float* base = dst + ((size_t)b * 65536 + (size_t)(h * 32 + w) * 64 + c * 32) * 32;
            #pragma unroll
            for (int reg = 0; reg < 16; reg++) {
                int row = (reg & 3) + 8 * (reg >> 2) + 4 * (l >> 5);
                base[row * 32 + o] = acc[tw][c][reg];
            }
        }
    }
}

extern "C" void kernel_launch(void* const* d_in, const int* in_sizes, int n_in,
                              void* d_out, int out_size, void* d_ws, size_t ws_size,
                              hipStream_t stream) {
    const float* wu   = (const float*)d_in[1];
    const float* buI  = (const float*)d_in[2];
    const float* wl   = (const float*)d_in[3];
    const float* blI  = (const float*)d_in[4];
    const float* kk   = (const float*)d_in[5];
    const float* bias = (const float*)d_in[6];

    float* out  = (float*)d_out;
    float* outU = out;
    float* buO  = out + 16777216;
    float* outL = out + 16777216 + 256;
    float* blO  = out + 2 * 16777216 + 256;

    uint16_t* ktb = (uint16_t*)d_ws;   // 73728 B

    k_prep<<<146, 256, 0, stream>>>(kk, ktb, buI, blI, buO, blO);
    k_main<<<2048, 256, 0, stream>>>(wu, wl, ktb, bias, outU, outL, buO, blO);
}

// Round 12
// 128.469 us; speedup vs baseline: 1.1369x; 1.0536x over previous
//
#include <hip/hip_runtime.h>
#include <cstdint>

typedef __attribute__((ext_vector_type(8))) short short8;
typedef __attribute__((ext_vector_type(16))) float f32x16;

__device__ inline uint32_t f2bf(float f) {
    union { float f; uint32_t u; } x; x.f = f;
    return (x.u + 0x7FFF + ((x.u >> 16) & 1)) >> 16;
}

// Convert kernel fp32 [9][64][64] -> bf16 ktb (same order), init bias outputs.
__global__ void k_prep(const float* __restrict__ kk, uint16_t* __restrict__ ktb,
                       const float* __restrict__ buI, const float* __restrict__ blI,
                       float* __restrict__ buO, float* __restrict__ blO) {
    int i = blockIdx.x * 256 + threadIdx.x;
    if (i < 36864) ktb[i] = (uint16_t)f2bf(kk[i]);
    else if (i < 36864 + 256) buO[i - 36864] = buI[i - 36864];
    else if (i < 36864 + 512) blO[i - 36864 - 256] = blI[i - 36864 - 256];
}

// ONE-WAVE blocks (64 threads), 8192 blocks = (b, UL, w-pair, h).
// R9 body verbatim: no LDS, no barriers, B-fragments direct from global.
// launch_bounds(64,3): 3 waves/SIMD (cap 170 unified; R9 body = 160 measured).
__global__ __launch_bounds__(64, 3) void k_main(
    const float* __restrict__ wu, const float* __restrict__ wl,
    const uint16_t* __restrict__ ktb, const float* __restrict__ bias,
    float* __restrict__ outU, float* __restrict__ outL,
    float* __restrict__ buO, float* __restrict__ blO)
{
    int l  = threadIdx.x;       // lane (block == one wave)
    int o  = l & 31;            // n_out index (frag col, stride-1 in memory)
    int ch = l >> 5;            // co-band selector

    // XCD-chunk decode: b = XCD id; within chunk h innermost, then w-pair, UL.
    int bid  = blockIdx.x;
    int virt = (bid & 7) * 1024 + (bid >> 3);
    int h    = virt & 31;
    int wp   = (virt >> 5) & 15;
    int UL   = (virt >> 9) & 1;
    int b    = virt >> 10;
    int w0   = wp * 2;            // wave's first owned w

    const float* src = UL ? wl : wu;
    float* dst  = UL ? outL : outU;
    float* bdst = UL ? blO : buO;

    float bp = 0.f;               // bias partial (this lane's o, its co-band)

    f32x16 acc[2][2];             // [tw][ci-half]
    #pragma unroll
    for (int a = 0; a < 2; a++)
        #pragma unroll
        for (int c = 0; c < 2; c++) acc[a][c] = (f32x16)0.f;

    // site validity (wave-uniform): ww = w0-1+si
    bool sv0 = (w0 != 0);         // si=0 OOB only when w0==0
    bool sv3 = (w0 != 30);        // si=3 OOB only when w0+2==32

    for (int r = 0; r < 3; r++) {
        int hh = h + 1 - r;                 // adjoint: out row h reads conv row h+1-kh
        if ((unsigned)hh >= 32u) continue;  // wave-uniform

        // per-site lane base pointers (floats): + co*32 + o, co = kidx*16 + ch*8 + e
        const float* sb[4];
        #pragma unroll
        for (int si = 0; si < 4; si++) {
            int ww = w0 - 1 + si;
            int wwc = ((unsigned)ww < 32u) ? ww : 0;
            sb[si] = src + ((size_t)b * 65536 + (size_t)(hh * 32 + wwc) * 64) * 32
                         + ch * 256 + o;
        }

        #pragma unroll
        for (int kidx = 0; kidx < 4; kidx++) {
            // A-fragments (verified layout), 6 x 16B from bf16 kernel
            short8 A[3][2];
            #pragma unroll
            for (int kw = 0; kw < 3; kw++)
                #pragma unroll
                for (int c = 0; c < 2; c++)
                    A[kw][c] = *(const short8*)&ktb[(((r * 3 + kw) * 64) + c * 32 + (l & 31)) * 64
                                                    + kidx * 16 + ch * 8];

            // issue all 4 sites' B loads (8 dwords each, imm-offset folded)
            float g[4][8];
            #pragma unroll
            for (int si = 0; si < 4; si++) {
                bool valid = (si == 0) ? sv0 : (si == 3) ? sv3 : true;
                if (valid) {
                    #pragma unroll
                    for (int e = 0; e < 8; e++)
                        g[si][e] = sb[si][kidx * 512 + e * 32];
                } else {
                    #pragma unroll
                    for (int e = 0; e < 8; e++) g[si][e] = 0.f;
                }
            }

            // bias: center row, wave's own columns (si=1 -> w0, si=2 -> w0+1)
            if (r == 1) {
                float4 b0 = *(const float4*)(bias + kidx * 16 + ch * 8);
                float4 b1 = *(const float4*)(bias + kidx * 16 + ch * 8 + 4);
                float bb[8] = {b0.x, b0.y, b0.z, b0.w, b1.x, b1.y, b1.z, b1.w};
                #pragma unroll
                for (int e = 0; e < 8; e++)
                    bp = fmaf(g[1][e], bb[e], fmaf(g[2][e], bb[e], bp));
            }

            // pack + MFMA
            #pragma unroll
            for (int si = 0; si < 4; si++) {
                short8 Bf;
                #pragma unroll
                for (int e = 0; e < 8; e++) Bf[e] = (short)(uint16_t)f2bf(g[si][e]);
                #pragma unroll
                for (int tw = 0; tw < 2; tw++) {
                    int kw = tw + 2 - si;              // compile-time under unroll
                    if (kw >= 0 && kw <= 2) {
                        #pragma unroll
                        for (int c = 0; c < 2; c++)
                            acc[tw][c] = __builtin_amdgcn_mfma_f32_32x32x16_bf16(
                                A[kw][c], Bf, acc[tw][c], 0, 0, 0);
                    }
                }
            }
        }
    }

    // ---- bias reduction: lanes l and l^32 share o ----
    bp += __shfl_xor(bp, 32);
    if (l < 32) atomicAdd(&bdst[b * 32 + o], bp);

    // ---- stores: col = o (coalesced), row = (reg&3)+8*(reg>>2)+4*(lane>>5) ----
    #pragma unroll
    for (int tw = 0; tw < 2; tw++) {
        int w = w0 + tw;
        #pragma unroll
        for (int c = 0; c < 2; c++) {
            float* base = dst + ((size_t)b * 65536 + (size_t)(h * 32 + w) * 64 + c * 32) * 32;
            #pragma unroll
            for (int reg = 0; reg < 16; reg++) {
                int row = (reg & 3) + 8 * (reg >> 2) + 4 * (l >> 5);
                base[row * 32 + o] = acc[tw][c][reg];
            }
        }
    }
}

extern "C" void kernel_launch(void* const* d_in, const int* in_sizes, int n_in,
                              void* d_out, int out_size, void* d_ws, size_t ws_size,
                              hipStream_t stream) {
    const float* wu   = (const float*)d_in[1];
    const float* buI  = (const float*)d_in[2];
    const float* wl   = (const float*)d_in[3];
    const float* blI  = (const float*)d_in[4];
    const float* kk   = (const float*)d_in[5];
    const float* bias = (const float*)d_in[6];

    float* out  = (float*)d_out;
    float* outU = out;
    float* buO  = out + 16777216;
    float* outL = out + 16777216 + 256;
    float* blO  = out + 2 * 16777216 + 256;

    uint16_t* ktb = (uint16_t*)d_ws;   // 73728 B

    k_prep<<<146, 256, 0, stream>>>(kk, ktb, buI, blI, buO, blO);
    k_main<<<8192, 64, 0, stream>>>(wu, wl, ktb, bias, outU, outL, buO, blO);
}